// Round 3
// 161.171 us; speedup vs baseline: 1.0146x; 1.0146x over previous
//
#include <hip/hip_runtime.h>
#include <math.h>

#define NH 16
#define HD 64
#define SEQ 2048
#define BAT 2
#define EMB 1024
#define MTOT (BAT*SEQ)   // 4096
#define NTOT (3*EMB)     // 3072
#define NT (EMB/64)      // 16 K-tiles of BK=64

typedef __attribute__((ext_vector_type(8))) short bf16x8;
typedef __attribute__((ext_vector_type(4))) float f32x4;

#define MFMA16(a,b,c) __builtin_amdgcn_mfma_f32_16x16x32_bf16(a,b,c,0,0,0)

__device__ inline short f2bf(float f) {
    union { float f; unsigned u; } x; x.f = f;
    unsigned r = (x.u + 0x7FFF + ((x.u >> 16) & 1)) >> 16;
    return (short)r;
}

// raw v_exp_f32 (inputs bounded to [-12,12]: no range/denorm handling needed)
__device__ inline float fast_exp2(float x) {
#if __has_builtin(__builtin_amdgcn_exp2f)
    return __builtin_amdgcn_exp2f(x);
#else
    float r; asm("v_exp_f32 %0, %1" : "=v"(r) : "v"(x)); return r;
#endif
}

// pack two f32 -> bf16x2 by TRUNCATION: single v_perm (P-weights; bias
// cancels in O/l ratio since l uses the same truncated P)
__device__ inline unsigned pack2bf_t(float a, float b) {
    union { float f; unsigned u; } x, y; x.f = a; y.f = b;
    return __builtin_amdgcn_perm(y.u, x.u, 0x07060302u);
}

typedef const __attribute__((address_space(1))) void* gp_t;
typedef __attribute__((address_space(3))) void* lp_t;
// async global->LDS, 16B/lane; LDS dest = wave-uniform base + lane*16
__device__ inline void gload16(const void* g, void* l) {
    __builtin_amdgcn_global_load_lds((gp_t)(uintptr_t)g, (lp_t)(uintptr_t)l, 16, 0, 0);
}

// raw barrier: compiler-level fence only (NO vmcnt drain -- this is the whole
// point of the counted-vmcnt pipeline; __syncthreads would emit vmcnt(0))
#define BARR() asm volatile("s_barrier" ::: "memory")
#define VMW(N) asm volatile("s_waitcnt vmcnt(" #N ")" ::: "memory")
#define LGKM0() asm volatile("s_waitcnt lgkmcnt(0)" ::: "memory")

// one phase's MFMA cluster: quadrant (MH, NHF), 16 MFMAs, ks outermost so
// the two dependent updates of each acc are 8 instructions apart
#define PHASE_MFMA(MH, BB, NHF)                                              \
    do {                                                                     \
        __builtin_amdgcn_s_setprio(1);                                       \
        _Pragma("unroll")                                                    \
        for (int ks = 0; ks < 2; ++ks)                                       \
            _Pragma("unroll")                                                \
            for (int mf4 = 0; mf4 < 4; ++mf4)                                \
                _Pragma("unroll")                                            \
                for (int nf2 = 0; nf2 < 2; ++nf2)                            \
                    acc[(MH)*4 + mf4][(NHF)*2 + nf2] =                       \
                        MFMA16(af[mf4][ks], BB[nf2][ks],                     \
                               acc[(MH)*4 + mf4][(NHF)*2 + nf2]);            \
        __builtin_amdgcn_s_setprio(0);                                       \
    } while (0)

// ---------------------------------------------------------------------------
// Prep: f32 -> bf16 for X (4M) and Wq|Wk|Wv (3M) into scratch carved from d_out.
// ---------------------------------------------------------------------------
__global__ __launch_bounds__(256) void prep_kernel(
    const float* __restrict__ x, const float* __restrict__ wq,
    const float* __restrict__ wk, const float* __restrict__ wv,
    short* __restrict__ xb, short* __restrict__ wb)
{
    const size_t NX = (size_t)MTOT * EMB;
    const size_t NW = (size_t)EMB * EMB;
    const size_t i4 = ((size_t)blockIdx.x * 256 + threadIdx.x) * 4;
    float4 v; short* dst;
    if (i4 < NX) { v = *(const float4*)(x + i4); dst = xb + i4; }
    else {
        size_t j = i4 - NX;
        const float* s = (j < NW) ? wq : (j < 2 * NW) ? wk : wv;
        v = *(const float4*)(s + (j & (NW - 1)));
        dst = wb + j;
    }
    short4 o; o.x = f2bf(v.x); o.y = f2bf(v.y); o.z = f2bf(v.z); o.w = f2bf(v.w);
    *(short4*)dst = o;
}

// ---------------------------------------------------------------------------
// Fused QKV GEMM: 256x256 tile, BK=64, 8 waves (2M x 4N), 4-phase-per-K-tile
// schedule (guide's m201 template): each phase = {ds-read reg subtile ||
// stage 1 chunk (2x global_load_lds w=16) -> s_barrier -> lgkmcnt(0) ->
// setprio(1) + 16 MFMA + setprio(0) -> s_barrier}, vmcnt checkpoint ONCE per
// K-tile at phase 4 (vmcnt(2): only kt+2's first chunk may stay in flight).
// Stage ledger: chunks h1..h3 of kt+1 at phases 1..3 (other buffer), h0 of
// kt+2 at phase 4 (current buffer -- its last ds_reads are phase 3's,
// certified complete by phase 3's closing barrier).
// LDS 128 KiB = 2 buf x [A0|A1|B0|B1] x 128x64 bf16, XOR-swizzled via
// pre-swizzled global source (linear gload_lds dest).
// Epilogue through LDS (256x256 bf16 T): fused Q/K L2-norm (wave's 64 cols =
// exactly one head) and V k-slot permute+transpose -- identical semantics to
// the 128^2 predecessor, attn_kernel unchanged.
// ---------------------------------------------------------------------------
__global__ __launch_bounds__(512, 2) void qkv_gemm_fast(
    const short* __restrict__ xb, const short* __restrict__ wb,
    short* __restrict__ qws, short* __restrict__ kws, short* __restrict__ vperm,
    const float* __restrict__ gptr)
{
    __shared__ short smem[65536];   // 128 KiB

    const int id = blockIdx.x;
    const int wg = (id & 7) * 24 + (id >> 3);   // XCD-chunked swizzle (192%8==0)
    const int m0 = (wg / 12) * 256;
    const int n0 = (wg % 12) * 256;
    const int t = threadIdx.x, wave = t >> 6, lane = t & 63;
    const int quad = lane >> 4, l16 = lane & 15;
    const int wr = wave >> 2, wc = wave & 3;    // wave tile: rows wr*128, cols wc*64

    // staging source (pre-swizzled global so the linear LDS dest lands swizzled)
    const int srow8 = lane >> 3;                 // row within 8-row gload group
    const int sgr = ((lane & 7) ^ srow8) * 8;    // swizzled col granule (shorts)
    const short* gA = xb + (size_t)(m0 + wave * 16 + srow8) * EMB + sgr;
    const short* gB = wb + (size_t)(n0 + wave * 16 + srow8) * EMB + sgr;

    auto stage_half = [&](int kt, int h, int pb) {   // h: 0=A0 1=A1 2=B0 3=B1
        short* ld = smem + pb * 32768 + h * 8192 + wave * 1024;
        const short* g = ((h < 2) ? gA + (size_t)(h * 128) * EMB
                                  : gB + (size_t)((h - 2) * 128) * EMB) + kt * 64;
        gload16(g, ld);
        gload16(g + (size_t)8 * EMB, ld + 512);
    };

    // fragment read offsets (relative to the wave's A-half / B-half base, shorts)
    int aoffs[4][2], boffs[4][2];
#pragma unroll
    for (int mf4 = 0; mf4 < 4; ++mf4)
#pragma unroll
        for (int ks = 0; ks < 2; ++ks)
            aoffs[mf4][ks] = (mf4 * 16 + l16) * 64 + (((ks * 4 + quad) ^ (l16 & 7)) * 8);
#pragma unroll
    for (int nf = 0; nf < 4; ++nf)
#pragma unroll
        for (int ks = 0; ks < 2; ++ks)
            boffs[nf][ks] = ((wc & 1) * 64 + nf * 16 + l16) * 64
                            + (((ks * 4 + quad) ^ (l16 & 7)) * 8);

    f32x4 acc[8][4] = {};
    bf16x8 af[4][2], b0[2][2], b1[2][2];

    // prologue: K-tile 0 fully (buf0) + K-tile 1 chunk A0 (buf1)
    stage_half(0, 0, 0); stage_half(0, 1, 0); stage_half(0, 2, 0); stage_half(0, 3, 0);
    stage_half(1, 0, 1);
    VMW(2);          // own kt0 loads done; cross-wave visibility via the barrier
    BARR();

#pragma unroll 1
    for (int kt = 0; kt < NT; ++kt) {
        const int pp = kt & 1, qq = pp ^ 1;
        const short* bufA = smem + pp * 32768 + wr * 8192;
        const short* bufB = smem + pp * 32768 + 16384 + (wc >> 1) * 8192;

        // ---- phase 1: quadrant (mh0, nh0); 12 ds_reads ----
#pragma unroll
        for (int mf4 = 0; mf4 < 4; ++mf4)
#pragma unroll
            for (int ks = 0; ks < 2; ++ks)
                af[mf4][ks] = *(const bf16x8*)(bufA + aoffs[mf4][ks]);
#pragma unroll
        for (int nf = 0; nf < 2; ++nf)
#pragma unroll
            for (int ks = 0; ks < 2; ++ks)
                b0[nf][ks] = *(const bf16x8*)(bufB + boffs[nf][ks]);
        if (kt + 1 < NT) stage_half(kt + 1, 1, qq);
        BARR();
        LGKM0();
        PHASE_MFMA(0, b0, 0);
        BARR();

        // ---- phase 2: (mh0, nh1); 4 ds_reads ----
#pragma unroll
        for (int nf = 0; nf < 2; ++nf)
#pragma unroll
            for (int ks = 0; ks < 2; ++ks)
                b1[nf][ks] = *(const bf16x8*)(bufB + boffs[2 + nf][ks]);
        if (kt + 1 < NT) stage_half(kt + 1, 2, qq);
        BARR();
        LGKM0();
        PHASE_MFMA(0, b1, 1);
        BARR();

        // ---- phase 3: (mh1, nh0); 8 ds_reads (b0 reused from regs) ----
#pragma unroll
        for (int mf4 = 0; mf4 < 4; ++mf4)
#pragma unroll
            for (int ks = 0; ks < 2; ++ks)
                af[mf4][ks] = *(const bf16x8*)(bufA + 4096 + aoffs[mf4][ks]);
        if (kt + 1 < NT) stage_half(kt + 1, 3, qq);
        BARR();
        LGKM0();
        PHASE_MFMA(1, b0, 0);
        BARR();

        // ---- phase 4: (mh1, nh1); 0 ds_reads; per-K-tile vmcnt checkpoint ----
        // stage kt+2's A0 into CURRENT buf (its last ds_reads were phase 3's,
        // certified by phase 3's closing barrier: a wave passing it has
        // executed its phase-3 MFMAs, hence its ds_reads completed)
        if (kt + 2 < NT) stage_half(kt + 2, 0, pp);
        BARR();
        PHASE_MFMA(1, b1, 1);
        if (kt + 2 < NT) { VMW(2); }   // kt+1 fully resident; kt+2-h0 in flight
        else             { VMW(0); }   // tail: drain everything
        BARR();
    }

    // ---- epilogue (through LDS, coalesced stores) ----
    short* T = smem;   // 256 x 256 bf16, 16B-granule XOR swizzle
    const int mat = n0 >> 10;   // 0=Q,1=K,2=V (block-uniform; tiles never straddle)

    if (mat < 2) {
        const float scale = (mat == 0) ? gptr[0] * 1.4426950408889634f : 1.0f;
#pragma unroll
        for (int mf = 0; mf < 8; ++mf) {
            float inv[4];
#pragma unroll
            for (int reg = 0; reg < 4; ++reg) {
                float ss = 0.f;
#pragma unroll
                for (int nf = 0; nf < 4; ++nf) { float v = acc[mf][nf][reg]; ss += v * v; }
                ss += __shfl_xor(ss, 1, 16);
                ss += __shfl_xor(ss, 2, 16);
                ss += __shfl_xor(ss, 4, 16);
                ss += __shfl_xor(ss, 8, 16);
                inv[reg] = scale / fmaxf(sqrtf(ss), 1e-12f);
            }
#pragma unroll
            for (int nf = 0; nf < 4; ++nf) {
                const int c = wc * 64 + nf * 16 + l16;
#pragma unroll
                for (int reg = 0; reg < 4; ++reg) {
                    const int s = wr * 128 + mf * 16 + quad * 4 + reg;
                    T[s * 256 + (((c >> 3) ^ (s & 15)) << 3) + (c & 7)] =
                        f2bf(acc[mf][nf][reg] * inv[reg]);
                }
            }
        }
        __syncthreads();   // ds_writes must be visible cross-wave (lgkm drain ok here)
        short* outp = (mat == 0) ? qws : kws;
        const int i2 = t & 7;   // granule within head-row: 8 lanes -> 128B contiguous
#pragma unroll
        for (int it = 0; it < 16; ++it) {
            const int rh = (t >> 3) + it * 64;    // row-head chunk 0..1023
            const int r = rh >> 2, hq = rh & 3;
            const int sg = m0 + r, bb = sg >> 11, sl = sg & (SEQ - 1);
            const int h = ((n0 & 1023) >> 6) + hq;
            short* orow = outp + ((size_t)(bb * NH + h) * SEQ + sl) * HD;
            int4 v = *(const int4*)&T[r * 256 + (((hq * 8 + i2) ^ (r & 15)) << 3)];
            *(int4*)&orow[i2 * 8] = v;
        }
    } else {
        // V: write rows at pos-permuted s (PV MFMA k-slot order), read
        // transposed, store contiguous -- identical net mapping to previous
        // kernel, attn_kernel's expectations unchanged
#pragma unroll
        for (int mf = 0; mf < 8; ++mf)
#pragma unroll
            for (int nf = 0; nf < 4; ++nf) {
                const int c = wc * 64 + nf * 16 + l16;
#pragma unroll
                for (int reg = 0; reg < 4; ++reg) {
                    const int s = wr * 128 + mf * 16 + quad * 4 + reg;
                    const int sp = (s & ~31) + ((s & 12) >> 2) * 8 + ((s >> 4) & 1) * 4 + (s & 3);
                    T[sp * 256 + (((c >> 3) ^ (sp & 15)) << 3) + (c & 7)] =
                        f2bf(acc[mf][nf][reg]);
                }
            }
        __syncthreads();
        const int c = t >> 1, half = t & 1;
        const int h = ((n0 & 1023) >> 6) + (c >> 6), d = c & 63;
        const int bb = m0 >> 11, p0 = (m0 & (SEQ - 1)) + half * 128;
        short* vrow = vperm + ((size_t)(bb * NH + h) * HD + d) * SEQ + p0;
        const int cg = c >> 3, ce = c & 7;
#pragma unroll
        for (int j = 0; j < 16; ++j) {
            union { int4 v; short s8[8]; } tmp;
#pragma unroll
            for (int e = 0; e < 8; ++e) {
                const int s = half * 128 + j * 8 + e;
                tmp.s8[e] = T[s * 256 + ((cg ^ (s & 15)) << 3) + ce];
            }
            *(int4*)&vrow[j * 8] = tmp.v;
        }
    }
}

// ---------------------------------------------------------------------------
// Attention, wave-specialized over keys: block = 64 q; wave (qh,kh) computes
// q-half qh (32 q) x key-strip kh (32 of each 64-key tile). K staged by qh=0
// waves, V by qh=1 waves; double-buffered; 2-way-max swizzles. S^T trick:
// P exits QK^T MFMA directly in PV A-operand layout. l via ones-MFMA.
// Truncating bf16 pack (1 v_perm). Partial O/l reduced across kh through LDS.
// Grid 1024; bh = (id&7)*4 + ((id>>3)&3) -> each XCD's L2 holds 4 bh's K/V.
// ---------------------------------------------------------------------------
__global__ __launch_bounds__(256, 4) void attn_kernel(
    const short* __restrict__ qws, const short* __restrict__ kws,
    const short* __restrict__ vperm, float* __restrict__ out)
{
    __shared__ short Kt[2][2][2048];   // [buf][kh][klocal*64 + dgrp_phys*8]
    __shared__ short Vt[2][2][2048];   // [buf][kh][d*32 + ug_phys*8]
    __shared__ float lbuf[64];

    const int id = blockIdx.x;
    const int bh = (id & 7) * 4 + ((id >> 3) & 3);
    const int qt = id >> 5;                        // 0..31
    const int b = bh >> 4, h = bh & (NH - 1);
    const size_t base = (size_t)bh * SEQ * HD;
    const int t = threadIdx.x, wave = t >> 6, lane = t & 63;
    const int quad = lane >> 4, l16 = lane & 15;
    const int qh = wave >> 1, kh = wave & 1;

    // Q B-frags (q = qt*64 + qh*32 + qsub*16 + l16), loaded once
    bf16x8 bq[2][2];
#pragma unroll
    for (int qsub = 0; qsub < 2; ++qsub) {
        const short* qp = qws + base +
            (size_t)(qt * 64 + qh * 32 + qsub * 16 + l16) * HD + quad * 8;
        bq[qsub][0] = *(const bf16x8*)(qp);
        bq[qsub][1] = *(const bf16x8*)(qp + 32);
    }
    bf16x8 ones;
#pragma unroll
    for (int i = 0; i < 8; ++i) ones[i] = (short)0x3F80;

    // frag read offsets (shorts, within this wave's kh region)
    int koff[2][2];   // [msub][ks]: K A-frag, key=msub*16+l16, d=ks*32+quad*8
#pragma unroll
    for (int msub = 0; msub < 2; ++msub)
#pragma unroll
        for (int ks = 0; ks < 2; ++ks)
            koff[msub][ks] = (msub * 16 + l16) * 64 + (((ks * 4 + quad) ^ (l16 & 7)) * 8);
    int voff[4];      // V B-frag: d=nt*16+l16, slot group = quad (phys ^ (d>>1)&3)
#pragma unroll
    for (int nt = 0; nt < 4; ++nt) {
        const int d = nt * 16 + l16;
        voff[nt] = d * 32 + ((quad ^ ((d >> 1) & 3)) * 8);
    }

    f32x4 o_acc[2][4] = {};   // [qsub][nt]
    f32x4 l_acc[2] = {};

    // stage tile tt (this wave's kh strip only) into buffer p
    auto stage = [&](int tt, int p) {
        if (qh == 0) {  // K strip: [32 keys][64 d], 4 gload16
#pragma unroll
            for (int j = 0; j < 4; ++j) {
                const int kl = j * 8 + (lane >> 3);
                const int row = tt * 64 + kh * 32 + kl;
                gload16(kws + base + (size_t)row * HD + (((lane & 7) ^ (kl & 7)) * 8),
                        &Kt[p][kh][j * 512 + lane * 8]);
            }
        } else {        // V strip: [64 d][32 slots], 4 gload16
#pragma unroll
            for (int j = 0; j < 4; ++j) {
                const int d = j * 16 + (lane >> 2);
                const int ug = (lane & 3) ^ ((d >> 1) & 3);
                gload16(vperm + base + (size_t)d * SEQ + tt * 64 + kh * 32 + ug * 8,
                        &Vt[p][kh][j * 512 + lane * 8]);
            }
        }
    };

    stage(0, 0);
    __syncthreads();   // tile 0 resident

    for (int tt = 0; tt < SEQ / 64; ++tt) {
        const int p = tt & 1;
        if (tt + 1 < SEQ / 64) stage(tt + 1, p ^ 1);   // prefetch overlaps compute
        const short* Kp = &Kt[p][kh][0];
        const short* Vp = &Vt[p][kh][0];

        // S^T: 32 keys (this strip) x 32 q (this half)
        f32x4 st[2][2];   // [msub][qsub]
#pragma unroll
        for (int msub = 0; msub < 2; ++msub) {
            bf16x8 a0 = *(const bf16x8*)(Kp + koff[msub][0]);
            bf16x8 a1 = *(const bf16x8*)(Kp + koff[msub][1]);
#pragma unroll
            for (int qsub = 0; qsub < 2; ++qsub) {
                f32x4 z = {};
                z = MFMA16(a0, bq[qsub][0], z);
                st[msub][qsub] = MFMA16(a1, bq[qsub][1], z);
            }
        }
        // V B-frags (shared across qsub)
        bf16x8 vf[4];
#pragma unroll
        for (int nt = 0; nt < 4; ++nt)
            vf[nt] = *(const bf16x8*)(Vp + voff[nt]);
        // exp + truncating pack -> P A-frag; l + O MFMAs
#pragma unroll
        for (int qsub = 0; qsub < 2; ++qsub) {
            bf16x8 pa;
            unsigned* pu = (unsigned*)&pa;
            pu[0] = pack2bf_t(fast_exp2(st[0][qsub][0]), fast_exp2(st[0][qsub][1]));
            pu[1] = pack2bf_t(fast_exp2(st[0][qsub][2]), fast_exp2(st[0][qsub][3]));
            pu[2] = pack2bf_t(fast_exp2(st[1][qsub][0]), fast_exp2(st[1][qsub][1]));
            pu[3] = pack2bf_t(fast_exp2(st[1][qsub][2]), fast_exp2(st[1][qsub][3]));
            l_acc[qsub] = MFMA16(pa, ones, l_acc[qsub]);
#pragma unroll
            for (int nt = 0; nt < 4; ++nt)
                o_acc[qsub][nt] = MFMA16(pa, vf[nt], o_acc[qsub][nt]);
        }
        __syncthreads();   // drains prefetch (after compute) + guards buffer reuse
    }

    // ---- cross-kh reduction (reuse Kt as 16 KB float buffer) ----
    float* red = (float*)&Kt[0][0][0];   // [qh][q_local 32][d 64]
    if (kh == 1) {
#pragma unroll
        for (int qsub = 0; qsub < 2; ++qsub) {
#pragma unroll
            for (int nt = 0; nt < 4; ++nt)
#pragma unroll
                for (int r = 0; r < 4; ++r)
                    red[qh * 2048 + (qsub * 16 + quad * 4 + r) * 64 + nt * 16 + l16] =
                        o_acc[qsub][nt][r];
            if (l16 == 0)
#pragma unroll
                for (int r = 0; r < 4; ++r)
                    lbuf[qh * 32 + qsub * 16 + quad * 4 + r] = l_acc[qsub][r];
        }
    }
    __syncthreads();
    if (kh == 0) {
#pragma unroll
        for (int qsub = 0; qsub < 2; ++qsub) {
            float linv[4];
#pragma unroll
            for (int r = 0; r < 4; ++r)
                linv[r] = 1.0f / (l_acc[qsub][r] + lbuf[qh * 32 + qsub * 16 + quad * 4 + r]);
            const int s = qt * 64 + qh * 32 + qsub * 16 + quad * 4;
            float* ob = out + ((size_t)b * SEQ + s) * EMB + h * HD + l16;
#pragma unroll
            for (int nt = 0; nt < 4; ++nt)
#pragma unroll
                for (int r = 0; r < 4; ++r) {
                    const float o = o_acc[qsub][nt][r] +
                        red[qh * 2048 + (qsub * 16 + quad * 4 + r) * 64 + nt * 16 + l16];
                    ob[(size_t)r * EMB + nt * 16] = o * linv[r];
                }
        }
    }
}

extern "C" void kernel_launch(void* const* d_in, const int* in_sizes, int n_in,
                              void* d_out, int out_size, void* d_ws, size_t ws_size,
                              hipStream_t stream) {
    (void)in_sizes; (void)n_in; (void)out_size; (void)ws_size;
    const float* x  = (const float*)d_in[0];
    const float* Wq = (const float*)d_in[1];
    const float* Wk = (const float*)d_in[2];
    const float* Wv = (const float*)d_in[3];
    const float* g  = (const float*)d_in[4];
    float* out = (float*)d_out;

    const size_t per = (size_t)BAT * NH * SEQ * HD;   // 4,194,304 elems
    short* qws   = (short*)d_ws;
    short* kws   = qws + per;
    short* vperm = kws + per;                          // ws: 25.2 MB total

    // bf16 staging lives in d_out (16.8 MB; attn fully overwrites it last)
    short* xb = (short*)out;                           // 4M shorts
    short* wb = xb + (size_t)MTOT * EMB;               // 3M shorts (7M <= 8.38M cap)

    prep_kernel<<<7168, 256, 0, stream>>>(x, Wq, Wk, Wv, xb, wb);
    qkv_gemm_fast<<<(MTOT / 256) * (NTOT / 256), 512, 0, stream>>>(
        xb, wb, qws, kws, vperm, g);
    attn_kernel<<<(SEQ / 64) * BAT * NH, 256, 0, stream>>>(qws, kws, vperm, out);
}

// Round 4
// 156.950 us; speedup vs baseline: 1.0419x; 1.0269x over previous
//
#include <hip/hip_runtime.h>
#include <math.h>

#define NH 16
#define HD 64
#define SEQ 2048
#define BAT 2
#define EMB 1024
#define MTOT (BAT*SEQ)   // 4096
#define NTOT (3*EMB)     // 3072

typedef __attribute__((ext_vector_type(8))) short bf16x8;
typedef __attribute__((ext_vector_type(4))) float f32x4;

#define MFMA16(a,b,c) __builtin_amdgcn_mfma_f32_16x16x32_bf16(a,b,c,0,0,0)

__device__ inline short f2bf(float f) {
    union { float f; unsigned u; } x; x.f = f;
    unsigned r = (x.u + 0x7FFF + ((x.u >> 16) & 1)) >> 16;
    return (short)r;
}

// raw v_exp_f32 (inputs bounded to [-12,12]: no range/denorm handling needed)
__device__ inline float fast_exp2(float x) {
#if __has_builtin(__builtin_amdgcn_exp2f)
    return __builtin_amdgcn_exp2f(x);
#else
    float r; asm("v_exp_f32 %0, %1" : "=v"(r) : "v"(x)); return r;
#endif
}

// pack two f32 -> bf16x2 by TRUNCATION: single v_perm (P-weights; bias
// cancels in O/l ratio since l uses the same truncated P)
__device__ inline unsigned pack2bf_t(float a, float b) {
    union { float f; unsigned u; } x, y; x.f = a; y.f = b;
    return __builtin_amdgcn_perm(y.u, x.u, 0x07060302u);
}

typedef const __attribute__((address_space(1))) void* gp_t;
typedef __attribute__((address_space(3))) void* lp_t;
// async global->LDS, 16B/lane; LDS dest = wave-uniform base + lane*16
__device__ inline void gload16(const void* g, void* l) {
    __builtin_amdgcn_global_load_lds((gp_t)(uintptr_t)g, (lp_t)(uintptr_t)l, 16, 0, 0);
}

// ---------------------------------------------------------------------------
// Prep: f32 -> bf16 for X (4M) and Wq|Wk|Wv (3M) into scratch carved from d_out.
// ---------------------------------------------------------------------------
__global__ __launch_bounds__(256) void prep_kernel(
    const float* __restrict__ x, const float* __restrict__ wq,
    const float* __restrict__ wk, const float* __restrict__ wv,
    short* __restrict__ xb, short* __restrict__ wb)
{
    const size_t NX = (size_t)MTOT * EMB;
    const size_t NW = (size_t)EMB * EMB;
    const size_t i4 = ((size_t)blockIdx.x * 256 + threadIdx.x) * 4;
    float4 v; short* dst;
    if (i4 < NX) { v = *(const float4*)(x + i4); dst = xb + i4; }
    else {
        size_t j = i4 - NX;
        const float* s = (j < NW) ? wq : (j < 2 * NW) ? wk : wv;
        v = *(const float4*)(s + (j & (NW - 1)));
        dst = wb + j;
    }
    short4 o; o.x = f2bf(v.x); o.y = f2bf(v.y); o.z = f2bf(v.z); o.w = f2bf(v.w);
    *(short4*)dst = o;
}

// ---------------------------------------------------------------------------
// Fused QKV GEMM: 128x128 tile, round-0's proven double-buffered single-
// barrier loop, but BK 64->32: LDS halves to 32 KB -> 4 blocks/CU resident
// (vs 2), 16 waves/CU of cross-block TLP to hide load/LDS latency, and the
// 768-block grid is perfectly balanced (3 blocks/CU of work). Same total
// LDS/L2 traffic and FLOPs; swizzle re-derived for 64B rows:
//   phys_granule = true_granule ^ ((row>>1)&3)   (2-way max on ds_read_b128)
// Staging: 2 gload16 per wave per matrix per step (instr j covers rows
// wave*32 + j*16 + (lane>>2), granule lane&3, source col pre-XORed).
// Epilogue identical to round-0 (T = 128x128 shorts = 16384 = exact smem fit).
// ---------------------------------------------------------------------------
__global__ __launch_bounds__(256, 4) void qkv_gemm_fast(
    const short* __restrict__ xb, const short* __restrict__ wb,
    short* __restrict__ qws, short* __restrict__ kws, short* __restrict__ vperm,
    const float* __restrict__ gptr)
{
    __shared__ short smem[2 * 2 * 128 * 32];   // [buf][As|Bs], 32 KB; reused as T[128][128]
    const int m0 = blockIdx.x * 128, n0 = blockIdx.y * 128;
    const int t = threadIdx.x, wave = t >> 6, lane = t & 63;
    const int quad = lane >> 4, l16 = lane & 15;
    const int wm = (wave & 1) * 64, wn = (wave >> 1) * 64;

    // staging decode: instr j covers rows wave*32 + j*16 + (lane>>2)
    const int srow = wave * 32 + (lane >> 2);
    const int scol = ((lane & 3) ^ ((lane >> 3) & 3)) * 8;   // pre-swizzled source granule
    const short* ga = xb + (size_t)(m0 + srow) * EMB + scol;
    const short* gb = wb + (size_t)(n0 + srow) * EMB + scol;

    // frag read offsets (buffer-relative, shorts); row>>1&3 == l16>>1&3 here
    const int swz = (quad ^ ((l16 >> 1) & 3)) * 8;
    int aoff[4], boff[4];
#pragma unroll
    for (int mf = 0; mf < 4; ++mf) aoff[mf] = (wm + mf * 16 + l16) * 32 + swz;
#pragma unroll
    for (int nf = 0; nf < 4; ++nf) boff[nf] = 4096 + (wn + nf * 16 + l16) * 32 + swz;

    f32x4 acc[4][4] = {};

    // stage K-step k0 into buffer p (8 KB A + 8 KB B)
    auto stageg = [&](int k0, int p) {
        short* lA = smem + p * 8192 + wave * 1024;
        short* lB = smem + p * 8192 + 4096 + wave * 1024;
#pragma unroll
        for (int j = 0; j < 2; ++j) {
            gload16(ga + k0 + (size_t)j * 16 * EMB, lA + j * 512);
            gload16(gb + k0 + (size_t)j * 16 * EMB, lB + j * 512);
        }
    };

    stageg(0, 0);
    __syncthreads();   // buffer 0 resident

    for (int it = 0; it < EMB / 32; ++it) {
        const int p = it & 1;
        if (it + 1 < EMB / 32) stageg((it + 1) * 32, p ^ 1);   // prefetch overlaps compute
        const short* base = smem + p * 8192;
        bf16x8 af[4], bfr[4];
#pragma unroll
        for (int i = 0; i < 4; ++i) af[i]  = *(const bf16x8*)(base + aoff[i]);
#pragma unroll
        for (int i = 0; i < 4; ++i) bfr[i] = *(const bf16x8*)(base + boff[i]);
#pragma unroll
        for (int mf = 0; mf < 4; ++mf)
#pragma unroll
            for (int nf = 0; nf < 4; ++nf)
                acc[mf][nf] = MFMA16(af[mf], bfr[nf], acc[mf][nf]);
        __syncthreads();   // drains prefetch (after compute) + guards buffer reuse
    }

    // ---- epilogue (through LDS, coalesced stores) ----
    short* T = smem;   // 128 rows x 128 cols bf16, 16B-granule XOR swizzle
    const int mat = n0 >> 10;   // 0=Q,1=K,2=V (block-uniform)

    if (mat < 2) {
        const float scale = (mat == 0) ? gptr[0] * 1.4426950408889634f : 1.0f;
        float inv[4][4];
#pragma unroll
        for (int mf = 0; mf < 4; ++mf)
#pragma unroll
            for (int reg = 0; reg < 4; ++reg) {
                float ss = 0.f;
#pragma unroll
                for (int nf = 0; nf < 4; ++nf) { float v = acc[mf][nf][reg]; ss += v * v; }
                ss += __shfl_xor(ss, 1, 16);
                ss += __shfl_xor(ss, 2, 16);
                ss += __shfl_xor(ss, 4, 16);
                ss += __shfl_xor(ss, 8, 16);
                inv[mf][reg] = scale / fmaxf(sqrtf(ss), 1e-12f);
            }
#pragma unroll
        for (int mf = 0; mf < 4; ++mf)
#pragma unroll
            for (int nf = 0; nf < 4; ++nf) {
                const int c = wn + nf * 16 + l16;
#pragma unroll
                for (int reg = 0; reg < 4; ++reg) {
                    const int s = wm + mf * 16 + quad * 4 + reg;
                    T[s * 128 + (((c >> 3) ^ (s & 15)) << 3) + (c & 7)] =
                        f2bf(acc[mf][nf][reg] * inv[mf][reg]);
                }
            }
        __syncthreads();
        short* outp = (mat == 0) ? qws : kws;
        const int r = t >> 1, half = t & 1;
        const int sg = m0 + r, bb = sg >> 11, sl = sg & (SEQ - 1);
        const int h = ((n0 & 1023) >> 6) + half;
        short* orow = outp + ((size_t)(bb * NH + h) * SEQ + sl) * HD;
#pragma unroll
        for (int j = 0; j < 8; ++j) {
            int4 v = *(const int4*)&T[r * 128 + ((((half * 8 + j)) ^ (r & 15)) << 3)];
            *(int4*)&orow[j * 8] = v;
        }
    } else {
        // V: write rows at pos-permuted s, read transposed, store contiguous
#pragma unroll
        for (int mf = 0; mf < 4; ++mf)
#pragma unroll
            for (int nf = 0; nf < 4; ++nf) {
                const int c = wn + nf * 16 + l16;
#pragma unroll
                for (int reg = 0; reg < 4; ++reg) {
                    const int s = wm + mf * 16 + quad * 4 + reg;
                    const int sp = (s & ~31) + ((s & 12) >> 2) * 8 + ((s >> 4) & 1) * 4 + (s & 3);
                    T[sp * 128 + (((c >> 3) ^ (sp & 15)) << 3) + (c & 7)] =
                        f2bf(acc[mf][nf][reg]);
                }
            }
        __syncthreads();
        const int c = t >> 1, half = t & 1;
        const int h = ((n0 & 1023) >> 6) + (c >> 6), d = c & 63;
        const int bb = m0 >> 11, p0 = (m0 & (SEQ - 1)) + half * 64;
        short* vrow = vperm + ((size_t)(bb * NH + h) * HD + d) * SEQ + p0;
        const int cg = c >> 3, ce = c & 7;
#pragma unroll
        for (int j = 0; j < 8; ++j) {
            union { int4 v; short s[8]; } tmp;
#pragma unroll
            for (int e = 0; e < 8; ++e) {
                const int s = half * 64 + j * 8 + e;
                tmp.s[e] = T[s * 128 + ((cg ^ (s & 15)) << 3) + ce];
            }
            *(int4*)&vrow[j * 8] = tmp.v;
        }
    }
}

// ---------------------------------------------------------------------------
// Attention, wave-specialized over keys: block = 64 q; wave (qh,kh) computes
// q-half qh (32 q) x key-strip kh (32 of each 64-key tile). K staged by qh=0
// waves, V by qh=1 waves; double-buffered; 2-way-max swizzles. S^T trick:
// P exits QK^T MFMA directly in PV A-operand layout. l via ones-MFMA.
// Truncating bf16 pack (1 v_perm). Partial O/l reduced across kh through LDS.
// Grid 1024; bh = (id&7)*4 + ((id>>3)&3) -> each XCD's L2 holds 4 bh's K/V.
// ---------------------------------------------------------------------------
__global__ __launch_bounds__(256, 4) void attn_kernel(
    const short* __restrict__ qws, const short* __restrict__ kws,
    const short* __restrict__ vperm, float* __restrict__ out)
{
    __shared__ short Kt[2][2][2048];   // [buf][kh][klocal*64 + dgrp_phys*8]
    __shared__ short Vt[2][2][2048];   // [buf][kh][d*32 + ug_phys*8]
    __shared__ float lbuf[64];

    const int id = blockIdx.x;
    const int bh = (id & 7) * 4 + ((id >> 3) & 3);
    const int qt = id >> 5;                        // 0..31
    const int b = bh >> 4, h = bh & (NH - 1);
    const size_t base = (size_t)bh * SEQ * HD;
    const int t = threadIdx.x, wave = t >> 6, lane = t & 63;
    const int quad = lane >> 4, l16 = lane & 15;
    const int qh = wave >> 1, kh = wave & 1;

    // Q B-frags (q = qt*64 + qh*32 + qsub*16 + l16), loaded once
    bf16x8 bq[2][2];
#pragma unroll
    for (int qsub = 0; qsub < 2; ++qsub) {
        const short* qp = qws + base +
            (size_t)(qt * 64 + qh * 32 + qsub * 16 + l16) * HD + quad * 8;
        bq[qsub][0] = *(const bf16x8*)(qp);
        bq[qsub][1] = *(const bf16x8*)(qp + 32);
    }
    bf16x8 ones;
#pragma unroll
    for (int i = 0; i < 8; ++i) ones[i] = (short)0x3F80;

    // frag read offsets (shorts, within this wave's kh region)
    int koff[2][2];   // [msub][ks]: K A-frag, key=msub*16+l16, d=ks*32+quad*8
#pragma unroll
    for (int msub = 0; msub < 2; ++msub)
#pragma unroll
        for (int ks = 0; ks < 2; ++ks)
            koff[msub][ks] = (msub * 16 + l16) * 64 + (((ks * 4 + quad) ^ (l16 & 7)) * 8);
    int voff[4];      // V B-frag: d=nt*16+l16, slot group = quad (phys ^ (d>>1)&3)
#pragma unroll
    for (int nt = 0; nt < 4; ++nt) {
        const int d = nt * 16 + l16;
        voff[nt] = d * 32 + ((quad ^ ((d >> 1) & 3)) * 8);
    }

    f32x4 o_acc[2][4] = {};   // [qsub][nt]
    f32x4 l_acc[2] = {};

    // stage tile tt (this wave's kh strip only) into buffer p
    auto stage = [&](int tt, int p) {
        if (qh == 0) {  // K strip: [32 keys][64 d], 4 gload16
#pragma unroll
            for (int j = 0; j < 4; ++j) {
                const int kl = j * 8 + (lane >> 3);
                const int row = tt * 64 + kh * 32 + kl;
                gload16(kws + base + (size_t)row * HD + (((lane & 7) ^ (kl & 7)) * 8),
                        &Kt[p][kh][j * 512 + lane * 8]);
            }
        } else {        // V strip: [64 d][32 slots], 4 gload16
#pragma unroll
            for (int j = 0; j < 4; ++j) {
                const int d = j * 16 + (lane >> 2);
                const int ug = (lane & 3) ^ ((d >> 1) & 3);
                gload16(vperm + base + (size_t)d * SEQ + tt * 64 + kh * 32 + ug * 8,
                        &Vt[p][kh][j * 512 + lane * 8]);
            }
        }
    };

    stage(0, 0);
    __syncthreads();   // tile 0 resident

    for (int tt = 0; tt < SEQ / 64; ++tt) {
        const int p = tt & 1;
        if (tt + 1 < SEQ / 64) stage(tt + 1, p ^ 1);   // prefetch overlaps compute
        const short* Kp = &Kt[p][kh][0];
        const short* Vp = &Vt[p][kh][0];

        // S^T: 32 keys (this strip) x 32 q (this half)
        f32x4 st[2][2];   // [msub][qsub]
#pragma unroll
        for (int msub = 0; msub < 2; ++msub) {
            bf16x8 a0 = *(const bf16x8*)(Kp + koff[msub][0]);
            bf16x8 a1 = *(const bf16x8*)(Kp + koff[msub][1]);
#pragma unroll
            for (int qsub = 0; qsub < 2; ++qsub) {
                f32x4 z = {};
                z = MFMA16(a0, bq[qsub][0], z);
                st[msub][qsub] = MFMA16(a1, bq[qsub][1], z);
            }
        }
        // V B-frags (shared across qsub)
        bf16x8 vf[4];
#pragma unroll
        for (int nt = 0; nt < 4; ++nt)
            vf[nt] = *(const bf16x8*)(Vp + voff[nt]);
        // exp + truncating pack -> P A-frag; l + O MFMAs
#pragma unroll
        for (int qsub = 0; qsub < 2; ++qsub) {
            bf16x8 pa;
            unsigned* pu = (unsigned*)&pa;
            pu[0] = pack2bf_t(fast_exp2(st[0][qsub][0]), fast_exp2(st[0][qsub][1]));
            pu[1] = pack2bf_t(fast_exp2(st[0][qsub][2]), fast_exp2(st[0][qsub][3]));
            pu[2] = pack2bf_t(fast_exp2(st[1][qsub][0]), fast_exp2(st[1][qsub][1]));
            pu[3] = pack2bf_t(fast_exp2(st[1][qsub][2]), fast_exp2(st[1][qsub][3]));
            l_acc[qsub] = MFMA16(pa, ones, l_acc[qsub]);
#pragma unroll
            for (int nt = 0; nt < 4; ++nt)
                o_acc[qsub][nt] = MFMA16(pa, vf[nt], o_acc[qsub][nt]);
        }
        __syncthreads();   // drains prefetch (after compute) + guards buffer reuse
    }

    // ---- cross-kh reduction (reuse Kt as 16 KB float buffer) ----
    float* red = (float*)&Kt[0][0][0];   // [qh][q_local 32][d 64]
    if (kh == 1) {
#pragma unroll
        for (int qsub = 0; qsub < 2; ++qsub) {
#pragma unroll
            for (int nt = 0; nt < 4; ++nt)
#pragma unroll
                for (int r = 0; r < 4; ++r)
                    red[qh * 2048 + (qsub * 16 + quad * 4 + r) * 64 + nt * 16 + l16] =
                        o_acc[qsub][nt][r];
            if (l16 == 0)
#pragma unroll
                for (int r = 0; r < 4; ++r)
                    lbuf[qh * 32 + qsub * 16 + quad * 4 + r] = l_acc[qsub][r];
        }
    }
    __syncthreads();
    if (kh == 0) {
#pragma unroll
        for (int qsub = 0; qsub < 2; ++qsub) {
            float linv[4];
#pragma unroll
            for (int r = 0; r < 4; ++r)
                linv[r] = 1.0f / (l_acc[qsub][r] + lbuf[qh * 32 + qsub * 16 + quad * 4 + r]);
            const int s = qt * 64 + qh * 32 + qsub * 16 + quad * 4;
            float* ob = out + ((size_t)b * SEQ + s) * EMB + h * HD + l16;
#pragma unroll
            for (int nt = 0; nt < 4; ++nt)
#pragma unroll
                for (int r = 0; r < 4; ++r) {
                    const float o = o_acc[qsub][nt][r] +
                        red[qh * 2048 + (qsub * 16 + quad * 4 + r) * 64 + nt * 16 + l16];
                    ob[(size_t)r * EMB + nt * 16] = o * linv[r];
                }
        }
    }
}

extern "C" void kernel_launch(void* const* d_in, const int* in_sizes, int n_in,
                              void* d_out, int out_size, void* d_ws, size_t ws_size,
                              hipStream_t stream) {
    (void)in_sizes; (void)n_in; (void)out_size; (void)ws_size;
    const float* x  = (const float*)d_in[0];
    const float* Wq = (const float*)d_in[1];
    const float* Wk = (const float*)d_in[2];
    const float* Wv = (const float*)d_in[3];
    const float* g  = (const float*)d_in[4];
    float* out = (float*)d_out;

    const size_t per = (size_t)BAT * NH * SEQ * HD;   // 4,194,304 elems
    short* qws   = (short*)d_ws;
    short* kws   = qws + per;
    short* vperm = kws + per;                          // ws: 25.2 MB total

    // bf16 staging lives in d_out (16.8 MB; attn fully overwrites it last)
    short* xb = (short*)out;                           // 4M shorts
    short* wb = xb + (size_t)MTOT * EMB;               // 3M shorts (7M <= 8.38M cap)

    prep_kernel<<<7168, 256, 0, stream>>>(x, Wq, Wk, Wv, xb, wb);
    qkv_gemm_fast<<<dim3(MTOT / 128, NTOT / 128), 256, 0, stream>>>(
        xb, wb, qws, kws, vperm, g);
    attn_kernel<<<(SEQ / 64) * BAT * NH, 256, 0, stream>>>(qws, kws, vperm, out);
}